// Round 11
// baseline (721.450 us; speedup 1.0000x reference)
//
#include <hip/hip_runtime.h>
#include <hip/hip_fp16.h>
#include <math.h>

#define N_NODES 50000
#define E_EDGES 800000
#define E2 (E_EDGES + N_NODES)
#define HID 128
#define HEADS 4
#define OUTC 64
#define DEPTH 4
#define NEG_SLOPE 0.2f
#define LN_EPS 1e-6f
#define RB 782            // row-blocks of 64 rows (ceil 50000/64)
#define NTILES (RB * 4)   // 16-row A tiles incl. padding (3128)

typedef float f32x4 __attribute__((ext_vector_type(4)));
typedef float f32x2 __attribute__((ext_vector_type(2)));
typedef _Float16 half8 __attribute__((ext_vector_type(8)));
typedef _Float16 half2v __attribute__((ext_vector_type(2)));
typedef short short8v __attribute__((ext_vector_type(8)));

// ---------------- CSR build ----------------

__global__ void k_deg(const int* __restrict__ ei, int* __restrict__ deg) {
    int e = blockIdx.x * 256 + threadIdx.x;
    if (e >= E2) return;
    int d = (e < E_EDGES) ? ei[E_EDGES + e] : (e - E_EDGES);
    atomicAdd(&deg[d], 1);
}

__global__ void k_scan_block(const int* __restrict__ deg, int* __restrict__ partial,
                             int* __restrict__ bsum, int n) {
    __shared__ int sm[1024];
    int i = blockIdx.x * 1024 + threadIdx.x;
    int v = (i < n) ? deg[i] : 0;
    sm[threadIdx.x] = v;
    __syncthreads();
    for (int off = 1; off < 1024; off <<= 1) {
        int t = (threadIdx.x >= off) ? sm[threadIdx.x - off] : 0;
        __syncthreads();
        sm[threadIdx.x] += t;
        __syncthreads();
    }
    if (i < n) partial[i] = sm[threadIdx.x];
    if (threadIdx.x == 1023) bsum[blockIdx.x] = sm[1023];
}

__global__ void k_scan_bsum(int* __restrict__ bsum, int nb) {
    if (threadIdx.x == 0 && blockIdx.x == 0) {
        int run = 0;
        for (int b = 0; b < nb; ++b) { int v = bsum[b]; bsum[b] = run; run += v; }
    }
}

__global__ void k_scan_fix(const int* __restrict__ deg, int* __restrict__ row_ptr,
                           const int* __restrict__ bsum, int n) {
    int i = blockIdx.x * 1024 + threadIdx.x;
    if (i < n) row_ptr[i] = row_ptr[i] - deg[i] + bsum[blockIdx.x];
    if (i == 0) row_ptr[n] = E2;
}

__global__ void k_fill(const int* __restrict__ ei, const int* __restrict__ row_ptr,
                       int* __restrict__ cur, int* __restrict__ csr_src,
                       int* __restrict__ csr_dst) {
    int e = blockIdx.x * 256 + threadIdx.x;
    if (e >= E2) return;
    int s, d;
    if (e < E_EDGES) { s = ei[e]; d = ei[E_EDGES + e]; } else { s = d = e - E_EDGES; }
    int pos = atomicAdd(&cur[d], 1);
    int j = row_ptr[d] + pos;
    csr_src[j] = s;
    csr_dst[j] = d;
}

// ---------------- input projection + LN -> fp16 A-frag layout (4 nodes/block) ----------------

__global__ __launch_bounds__(256) void k_in_proj_ln(const float* __restrict__ x,
                                                    const float* __restrict__ W,
                                                    const float* __restrict__ bias,
                                                    const float* __restrict__ gamma,
                                                    const float* __restrict__ beta,
                                                    float* __restrict__ h,
                                                    _Float16* __restrict__ lA) {
    int tid = threadIdx.x;
    int lane = tid & 63;
    int nd = blockIdx.x * 4 + (tid >> 6);
    const float* xr = x + nd * 3;
    float x0 = xr[0], x1 = xr[1], x2 = xr[2];
    int j0 = lane, j1 = lane + 64;
    float a = bias[j0] + x0 * W[j0] + x1 * W[HID + j0] + x2 * W[2 * HID + j0];
    float b = bias[j1] + x0 * W[j1] + x1 * W[HID + j1] + x2 * W[2 * HID + j1];
    size_t base = (size_t)nd * HID;
    h[base + j0] = a;
    h[base + j1] = b;
    float s = a + b;
    for (int o = 1; o < 64; o <<= 1) s += __shfl_xor(s, o);
    float mu = s * (1.0f / 128.0f);
    float da = a - mu, db = b - mu;
    float v = da * da + db * db;
    for (int o = 1; o < 64; o <<= 1) v += __shfl_xor(v, o);
    float rstd = rsqrtf(v * (1.0f / 128.0f) + LN_EPS);
    float va = da * rstd * gamma[j0] + beta[j0];
    float vb = db * rstd * gamma[j1] + beta[j1];
    half8 vh;
    for (int j = 0; j < 8; ++j) {
        int c = (lane & 15) * 8 + j;
        float s1 = __shfl(va, c & 63);
        float s2 = __shfl(vb, c & 63);
        float val = (c < 64) ? s1 : s2;
        vh[j] = (_Float16)val;
    }
    if (lane < 16) {
        int tile = nd >> 4, m = nd & 15;
        size_t off = (((size_t)tile * 4 + (lane >> 2)) * 64 + (lane & 3) * 16 + m) * 8;
        *(half8*)(lA + off) = vh;
    }
}

// ---------------- repack W_conv into fp16 MFMA B-fragment layout ----------------

__global__ void k_repackB(const float* __restrict__ W_conv,
                          _Float16* __restrict__ Bp) {
    int idx = blockIdx.x * 256 + threadIdx.x;
    if (idx >= DEPTH * 65536) return;
    int j     = idx & 7;
    int lane  = (idx >> 3) & 63;
    int kc    = (idx >> 9) & 3;
    int ntile = (idx >> 11) & 31;
    int layer = idx >> 16;
    int k = kc * 32 + (lane >> 4) * 8 + j;
    int n = ntile * 16 + (lane & 15);
    Bp[idx] = (_Float16)W_conv[(size_t)layer * 65536 + (size_t)k * 512 + n];
}

// ---------------- MFMA GEMM: one wave per 64-row block, by-loop over 8 col blocks ----------------
// fp16 MFMA; per-wave LDS transpose; xh stored fp8 e4m3; alpha partials via v_dot2_f32_f16.

__global__ __launch_bounds__(256) void k_gemm_mfma(const _Float16* __restrict__ lA,
                                                   const _Float16* __restrict__ Bp,
                                                   const float* __restrict__ att_s,
                                                   const float* __restrict__ att_d,
                                                   unsigned char* __restrict__ xh,
                                                   float* __restrict__ pS,
                                                   float* __restrict__ pD) {
    __shared__ __half tile[4][64 * 72];
    int tid = threadIdx.x;
    int lane = tid & 63;
    int w = tid >> 6;
    int rb = blockIdx.x * 4 + w;
    if (rb >= RB) rb = RB - 1;          // duplicate work; identical stores, benign
    int row0 = rb * 64;
    int quad = lane >> 4;
    int l15  = lane & 15;
    int g  = lane >> 3;
    int c8 = (lane & 7) * 8;
    __half* lt = tile[w];

    for (int by = 0; by < 8; ++by) {
        int hh   = by >> 1;
        int half = by & 1;

        f32x4 acc[4][4];
        for (int mt = 0; mt < 4; ++mt)
            for (int nt = 0; nt < 4; ++nt)
                acc[mt][nt] = (f32x4)(0.0f);

        for (int kc = 0; kc < 4; ++kc) {
            half8 a[4], b[4];
            for (int mt = 0; mt < 4; ++mt)
                a[mt] = *(const half8*)(lA + (((size_t)(rb * 4 + mt) * 4 + kc) * 64 + lane) * 8);
            for (int nt = 0; nt < 4; ++nt)
                b[nt] = *(const half8*)(Bp + (((size_t)(by * 4 + nt) * 4 + kc) * 64 + lane) * 8);
            for (int mt = 0; mt < 4; ++mt)
                for (int nt = 0; nt < 4; ++nt)
                    acc[mt][nt] = __builtin_amdgcn_mfma_f32_16x16x32_f16(a[mt], b[nt], acc[mt][nt], 0, 0, 0);
        }

        // phase 1: registers -> LDS (XOR swizzle); per-wave, no barrier
        for (int mt = 0; mt < 4; ++mt)
            for (int r = 0; r < 4; ++r) {
                int row = mt * 16 + quad * 4 + r;
                for (int nt = 0; nt < 4; ++nt) {
                    int colp = ((nt ^ quad) * 16) + l15;
                    lt[row * 72 + colp] = __float2half(acc[mt][nt][r]);
                }
            }

        // phase 2: fdot2 alpha partials + fp8-packed coalesced xh stores (8B/lane)
        half2v aS[4], aD[4];
        for (int jp = 0; jp < 4; ++jp) {
            int c = hh * HID + half * 64 + c8 + jp * 2;
            aS[jp][0] = (_Float16)att_s[c];     aS[jp][1] = (_Float16)att_s[c + 1];
            aD[jp][0] = (_Float16)att_d[c];     aD[jp][1] = (_Float16)att_d[c + 1];
        }
        for (int p = 0; p < 8; ++p) {
            int row = p * 8 + g;
            int q = (row >> 2) & 3;
            int colp = (((c8 >> 4) ^ q) * 16) + (c8 & 15);
            short8v vraw = *(const short8v*)(lt + row * 72 + colp);
            const half2v* vp = (const half2v*)&vraw;
            const __half* vh = (const __half*)&vraw;
            int grow = row0 + row;
            float ps = 0.f, pd = 0.f;
            for (int jp = 0; jp < 4; ++jp) {
                ps = __builtin_amdgcn_fdot2(vp[jp], aS[jp], ps, false);
                pd = __builtin_amdgcn_fdot2(vp[jp], aD[jp], pd, false);
            }
            if (grow < N_NODES) {
                float v0 = __half2float(vh[0]), v1 = __half2float(vh[1]);
                float v2 = __half2float(vh[2]), v3 = __half2float(vh[3]);
                float v4 = __half2float(vh[4]), v5 = __half2float(vh[5]);
                float v6 = __half2float(vh[6]), v7 = __half2float(vh[7]);
                int w0 = __builtin_amdgcn_cvt_pk_fp8_f32(v0, v1, 0, false);
                w0     = __builtin_amdgcn_cvt_pk_fp8_f32(v2, v3, w0, true);
                int w1 = __builtin_amdgcn_cvt_pk_fp8_f32(v4, v5, 0, false);
                w1     = __builtin_amdgcn_cvt_pk_fp8_f32(v6, v7, w1, true);
                *(int2*)(xh + (size_t)grow * 512 + by * 64 + c8) = make_int2(w0, w1);
            }
            ps += __shfl_xor(ps, 1); pd += __shfl_xor(pd, 1);
            ps += __shfl_xor(ps, 2); pd += __shfl_xor(pd, 2);
            ps += __shfl_xor(ps, 4); pd += __shfl_xor(pd, 4);
            if ((lane & 7) == 0 && grow < N_NODES) {
                pS[(size_t)grow * 8 + by] = ps;
                pD[(size_t)grow * 8 + by] = pd;
            }
        }
    }
}

// ---------------- per-edge softmax numerators (k_comb folded in) ----------------
// as[h] = pS[s*8+2h]+pS[s*8+2h+1]; ad[h] likewise from pD[dst].

__global__ __launch_bounds__(256) void k_edge(const int* __restrict__ csr_src,
                                              const int* __restrict__ csr_dst,
                                              const float* __restrict__ pS,
                                              const float* __restrict__ pD,
                                              float* __restrict__ p) {
    int j = blockIdx.x * 256 + threadIdx.x;
    if (j >= E2) return;
    int s = csr_src[j];
    int d = csr_dst[j];
    float4 sa = *(const float4*)(pS + (size_t)s * 8);
    float4 sb = *(const float4*)(pS + (size_t)s * 8 + 4);
    float4 da = *(const float4*)(pD + (size_t)d * 8);
    float4 db = *(const float4*)(pD + (size_t)d * 8 + 4);
    float4 r;
    float v;
    v = (sa.x + sa.y) + (da.x + da.y); v = (v >= 0.f) ? v : NEG_SLOPE * v; r.x = __expf(v);
    v = (sa.z + sa.w) + (da.z + da.w); v = (v >= 0.f) ? v : NEG_SLOPE * v; r.y = __expf(v);
    v = (sb.x + sb.y) + (db.x + db.y); v = (v >= 0.f) ? v : NEG_SLOPE * v; r.z = __expf(v);
    v = (sb.z + sb.w) + (db.z + db.w); v = (v >= 0.f) ? v : NEG_SLOPE * v; r.w = __expf(v);
    *(float4*)(p + (size_t)j * 4) = r;
}

// ---------------- per-node aggregate (fp8 gather, packed-f32 accum): 2 waves per node ----------------

__global__ __launch_bounds__(256) void k_agg(const unsigned char* __restrict__ xh,
                                             const float* __restrict__ p,
                                             const int* __restrict__ row_ptr,
                                             const int* __restrict__ csr_src,
                                             const float* __restrict__ bias,
                                             float* __restrict__ h,
                                             _Float16* __restrict__ lA,
                                             const float* __restrict__ gamma,
                                             const float* __restrict__ beta,
                                             int write_ln) {
    __shared__ float lds[2][64][9];
    int tid = threadIdx.x;
    int lane = tid & 63;
    int wv = tid >> 6;          // 0..3
    int nib = wv >> 1;          // node in block
    int half = wv & 1;
    int nd = blockIdx.x * 2 + nib;
    int start = row_ptr[nd], end = row_ptr[nd + 1];
    int mid = start + ((end - start + 1) >> 1);
    int s0 = half ? mid : start;
    int s1 = half ? end : mid;
    int hh = lane >> 4;

    f32x2 ac0 = (f32x2)(0.f), ac1 = (f32x2)(0.f), ac2 = (f32x2)(0.f), ac3 = (f32x2)(0.f);
    float z = 0.f;
    const unsigned char* xbase = xh + (size_t)lane * 8;

    int e = s0;
    for (; e + 4 <= s1; e += 4) {
        int src0 = csr_src[e], src1 = csr_src[e + 1], src2 = csr_src[e + 2], src3 = csr_src[e + 3];
        float p0 = p[(size_t)(e + 0) * 4 + hh];
        float p1 = p[(size_t)(e + 1) * 4 + hh];
        float p2 = p[(size_t)(e + 2) * 4 + hh];
        float p3 = p[(size_t)(e + 3) * 4 + hh];
        int2 w0 = *(const int2*)(xbase + (size_t)src0 * 512);
        int2 w1 = *(const int2*)(xbase + (size_t)src1 * 512);
        int2 w2 = *(const int2*)(xbase + (size_t)src2 * 512);
        int2 w3 = *(const int2*)(xbase + (size_t)src3 * 512);
        z += (p0 + p1) + (p2 + p3);
        f32x2 pv;
        pv = (f32x2)(p0);
        ac0 += pv * __builtin_amdgcn_cvt_pk_f32_fp8(w0.x, false);
        ac1 += pv * __builtin_amdgcn_cvt_pk_f32_fp8(w0.x, true);
        ac2 += pv * __builtin_amdgcn_cvt_pk_f32_fp8(w0.y, false);
        ac3 += pv * __builtin_amdgcn_cvt_pk_f32_fp8(w0.y, true);
        pv = (f32x2)(p1);
        ac0 += pv * __builtin_amdgcn_cvt_pk_f32_fp8(w1.x, false);
        ac1 += pv * __builtin_amdgcn_cvt_pk_f32_fp8(w1.x, true);
        ac2 += pv * __builtin_amdgcn_cvt_pk_f32_fp8(w1.y, false);
        ac3 += pv * __builtin_amdgcn_cvt_pk_f32_fp8(w1.y, true);
        pv = (f32x2)(p2);
        ac0 += pv * __builtin_amdgcn_cvt_pk_f32_fp8(w2.x, false);
        ac1 += pv * __builtin_amdgcn_cvt_pk_f32_fp8(w2.x, true);
        ac2 += pv * __builtin_amdgcn_cvt_pk_f32_fp8(w2.y, false);
        ac3 += pv * __builtin_amdgcn_cvt_pk_f32_fp8(w2.y, true);
        pv = (f32x2)(p3);
        ac0 += pv * __builtin_amdgcn_cvt_pk_f32_fp8(w3.x, false);
        ac1 += pv * __builtin_amdgcn_cvt_pk_f32_fp8(w3.x, true);
        ac2 += pv * __builtin_amdgcn_cvt_pk_f32_fp8(w3.y, false);
        ac3 += pv * __builtin_amdgcn_cvt_pk_f32_fp8(w3.y, true);
    }
    for (; e < s1; ++e) {
        int src0 = csr_src[e];
        float p0 = p[(size_t)e * 4 + hh];
        int2 w0 = *(const int2*)(xbase + (size_t)src0 * 512);
        z += p0;
        f32x2 pv = (f32x2)(p0);
        ac0 += pv * __builtin_amdgcn_cvt_pk_f32_fp8(w0.x, false);
        ac1 += pv * __builtin_amdgcn_cvt_pk_f32_fp8(w0.x, true);
        ac2 += pv * __builtin_amdgcn_cvt_pk_f32_fp8(w0.y, false);
        ac3 += pv * __builtin_amdgcn_cvt_pk_f32_fp8(w0.y, true);
    }

    float acc[8] = { ac0[0], ac0[1], ac1[0], ac1[1], ac2[0], ac2[1], ac3[0], ac3[1] };

    if (half) {
        for (int j = 0; j < 8; ++j) lds[nib][lane][j] = acc[j];
        lds[nib][lane][8] = z;
    }
    __syncthreads();
    if (half) return;
    for (int j = 0; j < 8; ++j) acc[j] += lds[nib][lane][j];
    z += lds[nib][lane][8];

    float inv = 1.0f / z;
    for (int j = 0; j < 8; ++j) acc[j] *= inv;
    for (int j = 0; j < 8; ++j) acc[j] += __shfl_xor(acc[j], 16);
    for (int j = 0; j < 8; ++j) acc[j] += __shfl_xor(acc[j], 32);

    int c = (lane & 15) * 8;
    float r[8];
    if (lane < 16) {
        float* hr = h + (size_t)nd * HID + c;
        const float* br = bias + c;
        for (int j = 0; j < 8; ++j) {
            float t = 0.25f * acc[j] + br[j];
            t = fmaxf(t, 0.f);
            r[j] = t + hr[j];
        }
        *(float4*)(hr)     = make_float4(r[0], r[1], r[2], r[3]);
        *(float4*)(hr + 4) = make_float4(r[4], r[5], r[6], r[7]);
    } else {
        for (int j = 0; j < 8; ++j) r[j] = 0.f;
    }

    if (write_ln) {
        float s = 0.f;
        for (int j = 0; j < 8; ++j) s += r[j];
        for (int o = 1; o < 16; o <<= 1) s += __shfl_xor(s, o);
        float mu = s * (1.0f / 128.0f);
        float var = 0.f;
        if (lane < 16)
            for (int j = 0; j < 8; ++j) { float d = r[j] - mu; var += d * d; }
        for (int o = 1; o < 16; o <<= 1) var += __shfl_xor(var, o);
        float rstd = rsqrtf(var * (1.0f / 128.0f) + LN_EPS);
        if (lane < 16) {
            half8 vh;
            for (int j = 0; j < 8; ++j)
                vh[j] = (_Float16)((r[j] - mu) * rstd * gamma[c + j] + beta[c + j]);
            int tile = nd >> 4, m = nd & 15;
            size_t off = (((size_t)tile * 4 + (lane >> 2)) * 64 + (lane & 3) * 16 + m) * 8;
            *(half8*)(lA + off) = vh;
        }
    }
}

// ---------------- output projection: LDS-staged W, 8 nodes/block, 2 nodes/thread ----------------

__global__ __launch_bounds__(256) void k_out_proj(const float* __restrict__ h,
                                                  const float* __restrict__ W,
                                                  const float* __restrict__ b,
                                                  float* __restrict__ out) {
    __shared__ float Ws[HID * OUTC];
    int tid = threadIdx.x;
    for (int it = 0; it < 8; ++it) {
        int idx = (tid + it * 256) * 4;
        *(float4*)&Ws[idx] = *(const float4*)(W + idx);
    }
    __syncthreads();
    int j = tid & 63;
    int sub = tid >> 6;
    int nd0 = blockIdx.x * 8 + sub * 2;
    const float* h0 = h + (size_t)nd0 * HID;
    const float* h1 = h0 + HID;
    float a0 = b[j], a1 = a0;
    #pragma unroll 8
    for (int k = 0; k < HID; ++k) {
        float w = Ws[k * OUTC + j];
        a0 += h0[k] * w;
        a1 += h1[k] * w;
    }
    out[(size_t)nd0 * OUTC + j]       = a0;
    out[(size_t)(nd0 + 1) * OUTC + j] = a1;
}

// ---------------- launch ----------------

extern "C" void kernel_launch(void* const* d_in, const int* in_sizes, int n_in,
                              void* d_out, int out_size, void* d_ws, size_t ws_size,
                              hipStream_t stream) {
    const float* x       = (const float*)d_in[0];
    const int*   ei      = (const int*)d_in[1];
    const float* W_in    = (const float*)d_in[2];
    const float* b_in    = (const float*)d_in[3];
    const float* W_conv  = (const float*)d_in[4];
    const float* att_src = (const float*)d_in[5];
    const float* att_dst = (const float*)d_in[6];
    const float* b_conv  = (const float*)d_in[7];
    const float* ln_g    = (const float*)d_in[8];
    const float* ln_b    = (const float*)d_in[9];
    const float* W_out   = (const float*)d_in[10];
    const float* b_out   = (const float*)d_in[11];
    float* out = (float*)d_out;

    char* ws = (char*)d_ws;
    size_t off = 0;
    auto alloc = [&](size_t bytes) { void* p = ws + off; off = (off + bytes + 255) & ~(size_t)255; return p; };
    float* h            = (float*)alloc((size_t)N_NODES * HID * 4);
    _Float16* lA        = (_Float16*)alloc((size_t)NTILES * 2048 * 2);
    unsigned char* xh   = (unsigned char*)alloc((size_t)N_NODES * 512);
    float* pS           = (float*)alloc((size_t)N_NODES * 8 * 4);
    float* pD           = (float*)alloc((size_t)N_NODES * 8 * 4);
    float* pedge        = (float*)alloc((size_t)E2 * HEADS * 4);
    _Float16* Bp        = (_Float16*)alloc((size_t)DEPTH * 65536 * 2);
    int* deg    = (int*)alloc((size_t)N_NODES * 4);
    int* cur    = (int*)alloc((size_t)N_NODES * 4);
    int* row_ptr= (int*)alloc((size_t)(N_NODES + 1) * 4);
    int* csr    = (int*)alloc((size_t)E2 * 4);
    int* csrd   = (int*)alloc((size_t)E2 * 4);
    int* bsum   = (int*)alloc(256 * 4);
    (void)ws_size; (void)n_in; (void)in_sizes; (void)out_size;

    hipMemsetAsync(deg, 0, (size_t)N_NODES * 4, stream);
    hipMemsetAsync(cur, 0, (size_t)N_NODES * 4, stream);

    // CSR build
    k_deg<<<(E2 + 255) / 256, 256, 0, stream>>>(ei, deg);
    int nb = (N_NODES + 1023) / 1024;
    k_scan_block<<<nb, 1024, 0, stream>>>(deg, row_ptr, bsum, N_NODES);
    k_scan_bsum<<<1, 64, 0, stream>>>(bsum, nb);
    k_scan_fix<<<nb, 1024, 0, stream>>>(deg, row_ptr, bsum, N_NODES);
    k_fill<<<(E2 + 255) / 256, 256, 0, stream>>>(ei, row_ptr, cur, csr, csrd);

    // weight repack (per call; graph-safe)
    k_repackB<<<(DEPTH * 65536 + 255) / 256, 256, 0, stream>>>(W_conv, Bp);

    // input projection + first LN (frag-packed fp16 output)
    k_in_proj_ln<<<N_NODES / 4, 256, 0, stream>>>(x, W_in, b_in, ln_g, ln_b, h, lA);

    // layers
    for (int i = 0; i < DEPTH; ++i) {
        const float* asp = att_src + (size_t)i * HEADS * HID;
        const float* adp = att_dst + (size_t)i * HEADS * HID;
        const float* bcp = b_conv + (size_t)i * HID;
        int write_ln = (i + 1 < DEPTH) ? 1 : 0;
        const float* gp = ln_g + (size_t)(i + 1 < DEPTH ? i + 1 : i) * HID;
        const float* bp = ln_b + (size_t)(i + 1 < DEPTH ? i + 1 : i) * HID;

        k_gemm_mfma<<<(RB + 3) / 4, 256, 0, stream>>>(lA, Bp + (size_t)i * 65536,
                                                      asp, adp, xh, pS, pD);
        k_edge<<<(E2 + 255) / 256, 256, 0, stream>>>(csr, csrd, pS, pD, pedge);
        k_agg<<<N_NODES / 2, 256, 0, stream>>>(xh, pedge, row_ptr, csr, bcp, h,
                                               lA, gp, bp, write_ln);
    }

    k_out_proj<<<N_NODES / 8, 256, 0, stream>>>(h, W_out, b_out, out);
}

// Round 12
// 688.546 us; speedup vs baseline: 1.0478x; 1.0478x over previous
//
#include <hip/hip_runtime.h>
#include <hip/hip_fp16.h>
#include <math.h>

#define N_NODES 50000
#define E_EDGES 800000
#define E2 (E_EDGES + N_NODES)
#define HID 128
#define HEADS 4
#define OUTC 64
#define DEPTH 4
#define NEG_SLOPE 0.2f
#define LN_EPS 1e-6f
#define RB 782            // row-blocks of 64 rows (ceil 50000/64)
#define NTILES (RB * 4)   // 16-row A tiles incl. padding (3128)

typedef float f32x4 __attribute__((ext_vector_type(4)));
typedef float f32x2 __attribute__((ext_vector_type(2)));
typedef _Float16 half8 __attribute__((ext_vector_type(8)));
typedef _Float16 half2v __attribute__((ext_vector_type(2)));
typedef short short8v __attribute__((ext_vector_type(8)));

// ---------------- CSR build ----------------

__global__ void k_deg(const int* __restrict__ ei, int* __restrict__ deg) {
    int e = blockIdx.x * 256 + threadIdx.x;
    if (e >= E2) return;
    int d = (e < E_EDGES) ? ei[E_EDGES + e] : (e - E_EDGES);
    atomicAdd(&deg[d], 1);
}

__global__ void k_scan_block(const int* __restrict__ deg, int* __restrict__ partial,
                             int* __restrict__ bsum, int n) {
    __shared__ int sm[1024];
    int i = blockIdx.x * 1024 + threadIdx.x;
    int v = (i < n) ? deg[i] : 0;
    sm[threadIdx.x] = v;
    __syncthreads();
    for (int off = 1; off < 1024; off <<= 1) {
        int t = (threadIdx.x >= off) ? sm[threadIdx.x - off] : 0;
        __syncthreads();
        sm[threadIdx.x] += t;
        __syncthreads();
    }
    if (i < n) partial[i] = sm[threadIdx.x];
    if (threadIdx.x == 1023) bsum[blockIdx.x] = sm[1023];
}

__global__ void k_scan_bsum(int* __restrict__ bsum, int nb) {
    if (threadIdx.x == 0 && blockIdx.x == 0) {
        int run = 0;
        for (int b = 0; b < nb; ++b) { int v = bsum[b]; bsum[b] = run; run += v; }
    }
}

__global__ void k_scan_fix(const int* __restrict__ deg, int* __restrict__ row_ptr,
                           const int* __restrict__ bsum, int n) {
    int i = blockIdx.x * 1024 + threadIdx.x;
    if (i < n) row_ptr[i] = row_ptr[i] - deg[i] + bsum[blockIdx.x];
    if (i == 0) row_ptr[n] = E2;
}

__global__ void k_fill(const int* __restrict__ ei, const int* __restrict__ row_ptr,
                       int* __restrict__ cur, int* __restrict__ csr_src,
                       int* __restrict__ csr_dst) {
    int e = blockIdx.x * 256 + threadIdx.x;
    if (e >= E2) return;
    int s, d;
    if (e < E_EDGES) { s = ei[e]; d = ei[E_EDGES + e]; } else { s = d = e - E_EDGES; }
    int pos = atomicAdd(&cur[d], 1);
    int j = row_ptr[d] + pos;
    csr_src[j] = s;
    csr_dst[j] = d;
}

// ---------------- input projection + LN -> fp16 A-frag layout (4 nodes/block) ----------------

__global__ __launch_bounds__(256) void k_in_proj_ln(const float* __restrict__ x,
                                                    const float* __restrict__ W,
                                                    const float* __restrict__ bias,
                                                    const float* __restrict__ gamma,
                                                    const float* __restrict__ beta,
                                                    float* __restrict__ h,
                                                    _Float16* __restrict__ lA) {
    int tid = threadIdx.x;
    int lane = tid & 63;
    int nd = blockIdx.x * 4 + (tid >> 6);
    const float* xr = x + nd * 3;
    float x0 = xr[0], x1 = xr[1], x2 = xr[2];
    int j0 = lane, j1 = lane + 64;
    float a = bias[j0] + x0 * W[j0] + x1 * W[HID + j0] + x2 * W[2 * HID + j0];
    float b = bias[j1] + x0 * W[j1] + x1 * W[HID + j1] + x2 * W[2 * HID + j1];
    size_t base = (size_t)nd * HID;
    h[base + j0] = a;
    h[base + j1] = b;
    float s = a + b;
    for (int o = 1; o < 64; o <<= 1) s += __shfl_xor(s, o);
    float mu = s * (1.0f / 128.0f);
    float da = a - mu, db = b - mu;
    float v = da * da + db * db;
    for (int o = 1; o < 64; o <<= 1) v += __shfl_xor(v, o);
    float rstd = rsqrtf(v * (1.0f / 128.0f) + LN_EPS);
    float va = da * rstd * gamma[j0] + beta[j0];
    float vb = db * rstd * gamma[j1] + beta[j1];
    half8 vh;
    for (int j = 0; j < 8; ++j) {
        int c = (lane & 15) * 8 + j;
        float s1 = __shfl(va, c & 63);
        float s2 = __shfl(vb, c & 63);
        float val = (c < 64) ? s1 : s2;
        vh[j] = (_Float16)val;
    }
    if (lane < 16) {
        int tile = nd >> 4, m = nd & 15;
        size_t off = (((size_t)tile * 4 + (lane >> 2)) * 64 + (lane & 3) * 16 + m) * 8;
        *(half8*)(lA + off) = vh;
    }
}

// ---------------- repack W_conv into fp16 MFMA B-fragment layout ----------------

__global__ void k_repackB(const float* __restrict__ W_conv,
                          _Float16* __restrict__ Bp) {
    int idx = blockIdx.x * 256 + threadIdx.x;
    if (idx >= DEPTH * 65536) return;
    int j     = idx & 7;
    int lane  = (idx >> 3) & 63;
    int kc    = (idx >> 9) & 3;
    int ntile = (idx >> 11) & 31;
    int layer = idx >> 16;
    int k = kc * 32 + (lane >> 4) * 8 + j;
    int n = ntile * 16 + (lane & 15);
    Bp[idx] = (_Float16)W_conv[(size_t)layer * 65536 + (size_t)k * 512 + n];
}

// ---------------- MFMA GEMM: one wave per (64-row, 64-col) tile; 2-D grid for occupancy ----------------
// fp16 MFMA; per-wave LDS transpose (no barriers); fdot2 alpha partials; fp8 xh stores.
// A re-reads across by-blocks are L3-absorbed (A = 25.6 MB << 256 MB L3).

__global__ __launch_bounds__(256) void k_gemm_mfma(const _Float16* __restrict__ lA,
                                                   const _Float16* __restrict__ Bp,
                                                   const float* __restrict__ att_s,
                                                   const float* __restrict__ att_d,
                                                   unsigned char* __restrict__ xh,
                                                   float* __restrict__ pS,
                                                   float* __restrict__ pD) {
    __shared__ __half tile[4][64 * 72];
    int tid = threadIdx.x;
    int lane = tid & 63;
    int w = tid >> 6;
    int rb = blockIdx.x * 4 + w;
    if (rb >= RB) rb = RB - 1;          // duplicate work; identical stores, benign
    int row0 = rb * 64;
    int by   = blockIdx.y;
    int quad = lane >> 4;
    int l15  = lane & 15;
    int g  = lane >> 3;
    int c8 = (lane & 7) * 8;
    __half* lt = tile[w];
    int hh   = by >> 1;
    int half = by & 1;

    f32x4 acc[4][4];
    for (int mt = 0; mt < 4; ++mt)
        for (int nt = 0; nt < 4; ++nt)
            acc[mt][nt] = (f32x4)(0.0f);

    for (int kc = 0; kc < 4; ++kc) {
        half8 a[4], b[4];
        for (int mt = 0; mt < 4; ++mt)
            a[mt] = *(const half8*)(lA + (((size_t)(rb * 4 + mt) * 4 + kc) * 64 + lane) * 8);
        for (int nt = 0; nt < 4; ++nt)
            b[nt] = *(const half8*)(Bp + (((size_t)(by * 4 + nt) * 4 + kc) * 64 + lane) * 8);
        for (int mt = 0; mt < 4; ++mt)
            for (int nt = 0; nt < 4; ++nt)
                acc[mt][nt] = __builtin_amdgcn_mfma_f32_16x16x32_f16(a[mt], b[nt], acc[mt][nt], 0, 0, 0);
    }

    // phase 1: registers -> LDS (XOR swizzle); per-wave, no barrier
    for (int mt = 0; mt < 4; ++mt)
        for (int r = 0; r < 4; ++r) {
            int row = mt * 16 + quad * 4 + r;
            for (int nt = 0; nt < 4; ++nt) {
                int colp = ((nt ^ quad) * 16) + l15;
                lt[row * 72 + colp] = __float2half(acc[mt][nt][r]);
            }
        }

    // phase 2: fdot2 alpha partials + fp8-packed coalesced xh stores (8B/lane)
    half2v aS[4], aD[4];
    for (int jp = 0; jp < 4; ++jp) {
        int c = hh * HID + half * 64 + c8 + jp * 2;
        aS[jp][0] = (_Float16)att_s[c];     aS[jp][1] = (_Float16)att_s[c + 1];
        aD[jp][0] = (_Float16)att_d[c];     aD[jp][1] = (_Float16)att_d[c + 1];
    }
    for (int p = 0; p < 8; ++p) {
        int row = p * 8 + g;
        int q = (row >> 2) & 3;
        int colp = (((c8 >> 4) ^ q) * 16) + (c8 & 15);
        short8v vraw = *(const short8v*)(lt + row * 72 + colp);
        const half2v* vp = (const half2v*)&vraw;
        const __half* vh = (const __half*)&vraw;
        int grow = row0 + row;
        float ps = 0.f, pd = 0.f;
        for (int jp = 0; jp < 4; ++jp) {
            ps = __builtin_amdgcn_fdot2(vp[jp], aS[jp], ps, false);
            pd = __builtin_amdgcn_fdot2(vp[jp], aD[jp], pd, false);
        }
        if (grow < N_NODES) {
            float v0 = __half2float(vh[0]), v1 = __half2float(vh[1]);
            float v2 = __half2float(vh[2]), v3 = __half2float(vh[3]);
            float v4 = __half2float(vh[4]), v5 = __half2float(vh[5]);
            float v6 = __half2float(vh[6]), v7 = __half2float(vh[7]);
            int w0 = __builtin_amdgcn_cvt_pk_fp8_f32(v0, v1, 0, false);
            w0     = __builtin_amdgcn_cvt_pk_fp8_f32(v2, v3, w0, true);
            int w1 = __builtin_amdgcn_cvt_pk_fp8_f32(v4, v5, 0, false);
            w1     = __builtin_amdgcn_cvt_pk_fp8_f32(v6, v7, w1, true);
            *(int2*)(xh + (size_t)grow * 512 + by * 64 + c8) = make_int2(w0, w1);
        }
        ps += __shfl_xor(ps, 1); pd += __shfl_xor(pd, 1);
        ps += __shfl_xor(ps, 2); pd += __shfl_xor(pd, 2);
        ps += __shfl_xor(ps, 4); pd += __shfl_xor(pd, 4);
        if ((lane & 7) == 0 && grow < N_NODES) {
            pS[(size_t)grow * 8 + by] = ps;
            pD[(size_t)grow * 8 + by] = pd;
        }
    }
}

// ---------------- per-edge softmax numerators (k_comb folded in) ----------------

__global__ __launch_bounds__(256) void k_edge(const int* __restrict__ csr_src,
                                              const int* __restrict__ csr_dst,
                                              const float* __restrict__ pS,
                                              const float* __restrict__ pD,
                                              float* __restrict__ p) {
    int j = blockIdx.x * 256 + threadIdx.x;
    if (j >= E2) return;
    int s = csr_src[j];
    int d = csr_dst[j];
    float4 sa = *(const float4*)(pS + (size_t)s * 8);
    float4 sb = *(const float4*)(pS + (size_t)s * 8 + 4);
    float4 da = *(const float4*)(pD + (size_t)d * 8);
    float4 db = *(const float4*)(pD + (size_t)d * 8 + 4);
    float4 r;
    float v;
    v = (sa.x + sa.y) + (da.x + da.y); v = (v >= 0.f) ? v : NEG_SLOPE * v; r.x = __expf(v);
    v = (sa.z + sa.w) + (da.z + da.w); v = (v >= 0.f) ? v : NEG_SLOPE * v; r.y = __expf(v);
    v = (sb.x + sb.y) + (db.x + db.y); v = (v >= 0.f) ? v : NEG_SLOPE * v; r.z = __expf(v);
    v = (sb.z + sb.w) + (db.z + db.w); v = (v >= 0.f) ? v : NEG_SLOPE * v; r.w = __expf(v);
    *(float4*)(p + (size_t)j * 4) = r;
}

// ---------------- per-node aggregate (fp8 gather, packed-f32 accum): 2 waves per node ----------------

__global__ __launch_bounds__(256) void k_agg(const unsigned char* __restrict__ xh,
                                             const float* __restrict__ p,
                                             const int* __restrict__ row_ptr,
                                             const int* __restrict__ csr_src,
                                             const float* __restrict__ bias,
                                             float* __restrict__ h,
                                             _Float16* __restrict__ lA,
                                             const float* __restrict__ gamma,
                                             const float* __restrict__ beta,
                                             int write_ln) {
    __shared__ float lds[2][64][9];
    int tid = threadIdx.x;
    int lane = tid & 63;
    int wv = tid >> 6;          // 0..3
    int nib = wv >> 1;          // node in block
    int half = wv & 1;
    int nd = blockIdx.x * 2 + nib;
    int start = row_ptr[nd], end = row_ptr[nd + 1];
    int mid = start + ((end - start + 1) >> 1);
    int s0 = half ? mid : start;
    int s1 = half ? end : mid;
    int hh = lane >> 4;

    f32x2 ac0 = (f32x2)(0.f), ac1 = (f32x2)(0.f), ac2 = (f32x2)(0.f), ac3 = (f32x2)(0.f);
    float z = 0.f;
    const unsigned char* xbase = xh + (size_t)lane * 8;

    int e = s0;
    for (; e + 4 <= s1; e += 4) {
        int src0 = csr_src[e], src1 = csr_src[e + 1], src2 = csr_src[e + 2], src3 = csr_src[e + 3];
        float p0 = p[(size_t)(e + 0) * 4 + hh];
        float p1 = p[(size_t)(e + 1) * 4 + hh];
        float p2 = p[(size_t)(e + 2) * 4 + hh];
        float p3 = p[(size_t)(e + 3) * 4 + hh];
        int2 w0 = *(const int2*)(xbase + (size_t)src0 * 512);
        int2 w1 = *(const int2*)(xbase + (size_t)src1 * 512);
        int2 w2 = *(const int2*)(xbase + (size_t)src2 * 512);
        int2 w3 = *(const int2*)(xbase + (size_t)src3 * 512);
        z += (p0 + p1) + (p2 + p3);
        f32x2 pv;
        pv = (f32x2)(p0);
        ac0 += pv * __builtin_amdgcn_cvt_pk_f32_fp8(w0.x, false);
        ac1 += pv * __builtin_amdgcn_cvt_pk_f32_fp8(w0.x, true);
        ac2 += pv * __builtin_amdgcn_cvt_pk_f32_fp8(w0.y, false);
        ac3 += pv * __builtin_amdgcn_cvt_pk_f32_fp8(w0.y, true);
        pv = (f32x2)(p1);
        ac0 += pv * __builtin_amdgcn_cvt_pk_f32_fp8(w1.x, false);
        ac1 += pv * __builtin_amdgcn_cvt_pk_f32_fp8(w1.x, true);
        ac2 += pv * __builtin_amdgcn_cvt_pk_f32_fp8(w1.y, false);
        ac3 += pv * __builtin_amdgcn_cvt_pk_f32_fp8(w1.y, true);
        pv = (f32x2)(p2);
        ac0 += pv * __builtin_amdgcn_cvt_pk_f32_fp8(w2.x, false);
        ac1 += pv * __builtin_amdgcn_cvt_pk_f32_fp8(w2.x, true);
        ac2 += pv * __builtin_amdgcn_cvt_pk_f32_fp8(w2.y, false);
        ac3 += pv * __builtin_amdgcn_cvt_pk_f32_fp8(w2.y, true);
        pv = (f32x2)(p3);
        ac0 += pv * __builtin_amdgcn_cvt_pk_f32_fp8(w3.x, false);
        ac1 += pv * __builtin_amdgcn_cvt_pk_f32_fp8(w3.x, true);
        ac2 += pv * __builtin_amdgcn_cvt_pk_f32_fp8(w3.y, false);
        ac3 += pv * __builtin_amdgcn_cvt_pk_f32_fp8(w3.y, true);
    }
    for (; e < s1; ++e) {
        int src0 = csr_src[e];
        float p0 = p[(size_t)e * 4 + hh];
        int2 w0 = *(const int2*)(xbase + (size_t)src0 * 512);
        z += p0;
        f32x2 pv = (f32x2)(p0);
        ac0 += pv * __builtin_amdgcn_cvt_pk_f32_fp8(w0.x, false);
        ac1 += pv * __builtin_amdgcn_cvt_pk_f32_fp8(w0.x, true);
        ac2 += pv * __builtin_amdgcn_cvt_pk_f32_fp8(w0.y, false);
        ac3 += pv * __builtin_amdgcn_cvt_pk_f32_fp8(w0.y, true);
    }

    float acc[8] = { ac0[0], ac0[1], ac1[0], ac1[1], ac2[0], ac2[1], ac3[0], ac3[1] };

    if (half) {
        for (int j = 0; j < 8; ++j) lds[nib][lane][j] = acc[j];
        lds[nib][lane][8] = z;
    }
    __syncthreads();
    if (half) return;
    for (int j = 0; j < 8; ++j) acc[j] += lds[nib][lane][j];
    z += lds[nib][lane][8];

    float inv = 1.0f / z;
    for (int j = 0; j < 8; ++j) acc[j] *= inv;
    for (int j = 0; j < 8; ++j) acc[j] += __shfl_xor(acc[j], 16);
    for (int j = 0; j < 8; ++j) acc[j] += __shfl_xor(acc[j], 32);

    int c = (lane & 15) * 8;
    float r[8];
    if (lane < 16) {
        float* hr = h + (size_t)nd * HID + c;
        const float* br = bias + c;
        for (int j = 0; j < 8; ++j) {
            float t = 0.25f * acc[j] + br[j];
            t = fmaxf(t, 0.f);
            r[j] = t + hr[j];
        }
        *(float4*)(hr)     = make_float4(r[0], r[1], r[2], r[3]);
        *(float4*)(hr + 4) = make_float4(r[4], r[5], r[6], r[7]);
    } else {
        for (int j = 0; j < 8; ++j) r[j] = 0.f;
    }

    if (write_ln) {
        float s = 0.f;
        for (int j = 0; j < 8; ++j) s += r[j];
        for (int o = 1; o < 16; o <<= 1) s += __shfl_xor(s, o);
        float mu = s * (1.0f / 128.0f);
        float var = 0.f;
        if (lane < 16)
            for (int j = 0; j < 8; ++j) { float d = r[j] - mu; var += d * d; }
        for (int o = 1; o < 16; o <<= 1) var += __shfl_xor(var, o);
        float rstd = rsqrtf(var * (1.0f / 128.0f) + LN_EPS);
        if (lane < 16) {
            half8 vh;
            for (int j = 0; j < 8; ++j)
                vh[j] = (_Float16)((r[j] - mu) * rstd * gamma[c + j] + beta[c + j]);
            int tile = nd >> 4, m = nd & 15;
            size_t off = (((size_t)tile * 4 + (lane >> 2)) * 64 + (lane & 3) * 16 + m) * 8;
            *(half8*)(lA + off) = vh;
        }
    }
}

// ---------------- output projection: LDS-staged W, 8 nodes/block, 2 nodes/thread ----------------

__global__ __launch_bounds__(256) void k_out_proj(const float* __restrict__ h,
                                                  const float* __restrict__ W,
                                                  const float* __restrict__ b,
                                                  float* __restrict__ out) {
    __shared__ float Ws[HID * OUTC];
    int tid = threadIdx.x;
    for (int it = 0; it < 8; ++it) {
        int idx = (tid + it * 256) * 4;
        *(float4*)&Ws[idx] = *(const float4*)(W + idx);
    }
    __syncthreads();
    int j = tid & 63;
    int sub = tid >> 6;
    int nd0 = blockIdx.x * 8 + sub * 2;
    const float* h0 = h + (size_t)nd0 * HID;
    const float* h1 = h0 + HID;
    float a0 = b[j], a1 = a0;
    #pragma unroll 8
    for (int k = 0; k < HID; ++k) {
        float w = Ws[k * OUTC + j];
        a0 += h0[k] * w;
        a1 += h1[k] * w;
    }
    out[(size_t)nd0 * OUTC + j]       = a0;
    out[(size_t)(nd0 + 1) * OUTC + j] = a1;
}

// ---------------- launch ----------------

extern "C" void kernel_launch(void* const* d_in, const int* in_sizes, int n_in,
                              void* d_out, int out_size, void* d_ws, size_t ws_size,
                              hipStream_t stream) {
    const float* x       = (const float*)d_in[0];
    const int*   ei      = (const int*)d_in[1];
    const float* W_in    = (const float*)d_in[2];
    const float* b_in    = (const float*)d_in[3];
    const float* W_conv  = (const float*)d_in[4];
    const float* att_src = (const float*)d_in[5];
    const float* att_dst = (const float*)d_in[6];
    const float* b_conv  = (const float*)d_in[7];
    const float* ln_g    = (const float*)d_in[8];
    const float* ln_b    = (const float*)d_in[9];
    const float* W_out   = (const float*)d_in[10];
    const float* b_out   = (const float*)d_in[11];
    float* out = (float*)d_out;

    char* ws = (char*)d_ws;
    size_t off = 0;
    auto alloc = [&](size_t bytes) { void* p = ws + off; off = (off + bytes + 255) & ~(size_t)255; return p; };
    float* h            = (float*)alloc((size_t)N_NODES * HID * 4);
    _Float16* lA        = (_Float16*)alloc((size_t)NTILES * 2048 * 2);
    unsigned char* xh   = (unsigned char*)alloc((size_t)N_NODES * 512);
    float* pS           = (float*)alloc((size_t)N_NODES * 8 * 4);
    float* pD           = (float*)alloc((size_t)N_NODES * 8 * 4);
    float* pedge        = (float*)alloc((size_t)E2 * HEADS * 4);
    _Float16* Bp        = (_Float16*)alloc((size_t)DEPTH * 65536 * 2);
    int* deg    = (int*)alloc((size_t)N_NODES * 4);
    int* cur    = (int*)alloc((size_t)N_NODES * 4);
    int* row_ptr= (int*)alloc((size_t)(N_NODES + 1) * 4);
    int* csr    = (int*)alloc((size_t)E2 * 4);
    int* csrd   = (int*)alloc((size_t)E2 * 4);
    int* bsum   = (int*)alloc(256 * 4);
    (void)ws_size; (void)n_in; (void)in_sizes; (void)out_size;

    hipMemsetAsync(deg, 0, (size_t)N_NODES * 4, stream);
    hipMemsetAsync(cur, 0, (size_t)N_NODES * 4, stream);

    // CSR build
    k_deg<<<(E2 + 255) / 256, 256, 0, stream>>>(ei, deg);
    int nb = (N_NODES + 1023) / 1024;
    k_scan_block<<<nb, 1024, 0, stream>>>(deg, row_ptr, bsum, N_NODES);
    k_scan_bsum<<<1, 64, 0, stream>>>(bsum, nb);
    k_scan_fix<<<nb, 1024, 0, stream>>>(deg, row_ptr, bsum, N_NODES);
    k_fill<<<(E2 + 255) / 256, 256, 0, stream>>>(ei, row_ptr, cur, csr, csrd);

    // weight repack (per call; graph-safe)
    k_repackB<<<(DEPTH * 65536 + 255) / 256, 256, 0, stream>>>(W_conv, Bp);

    // input projection + first LN (frag-packed fp16 output)
    k_in_proj_ln<<<N_NODES / 4, 256, 0, stream>>>(x, W_in, b_in, ln_g, ln_b, h, lA);

    // layers
    for (int i = 0; i < DEPTH; ++i) {
        const float* asp = att_src + (size_t)i * HEADS * HID;
        const float* adp = att_dst + (size_t)i * HEADS * HID;
        const float* bcp = b_conv + (size_t)i * HID;
        int write_ln = (i + 1 < DEPTH) ? 1 : 0;
        const float* gp = ln_g + (size_t)(i + 1 < DEPTH ? i + 1 : i) * HID;
        const float* bp = ln_b + (size_t)(i + 1 < DEPTH ? i + 1 : i) * HID;

        dim3 gg((RB + 3) / 4, 8);
        k_gemm_mfma<<<gg, 256, 0, stream>>>(lA, Bp + (size_t)i * 65536,
                                            asp, adp, xh, pS, pD);
        k_edge<<<(E2 + 255) / 256, 256, 0, stream>>>(csr, csrd, pS, pD, pedge);
        k_agg<<<N_NODES / 2, 256, 0, stream>>>(xh, pedge, row_ptr, csr, bcp, h,
                                               lA, gp, bp, write_ln);
    }

    k_out_proj<<<N_NODES / 8, 256, 0, stream>>>(h, W_out, b_out, out);
}